// Round 7
// baseline (618.257 us; speedup 1.0000x reference)
//
#include <hip/hip_runtime.h>
#include <stdint.h>

// 2-layer LSTM, B=64, T=1024, D=512, H=32, fp32 in/out.
// Phase 1: xg0 = x @ Wih0^T + b0  (fp32 tiled GEMM)
// Phase 2: fused 2-layer scan, ONE WAVE per batch, zero barriers/LDS.
//   Gate dots: v_pk_fma_f16 chains (full-rate packed math), f32 merge via
//   a few v_dot2_f32_f16. Cross-lane: permlane32_swap + DPP only.

#define TT 1024
#define BB 64
#define DD 512
#define HH 32
#define GG 128  // 4*H

typedef _Float16 h2v __attribute__((ext_vector_type(2)));
typedef __fp16 pk2 __attribute__((ext_vector_type(2)));
typedef int int2v __attribute__((ext_vector_type(2)));

#define H2(x) __builtin_bit_cast(h2v, x)
#define U32(x) __builtin_bit_cast(uint32_t, x)
#define ONE2 0x3C003C00u  // {1.0h, 1.0h}

__device__ __forceinline__ uint32_t pack2(float lo, float hi) {
  pk2 p = __builtin_amdgcn_cvt_pkrtz(lo, hi);
  return __builtin_bit_cast(uint32_t, p);
}
__device__ __forceinline__ float dot2(uint32_t a, uint32_t b, float acc) {
  return __builtin_amdgcn_fdot2(H2(a), H2(b), acc, false);
}
__device__ __forceinline__ float fast_rcp(float x) { return __builtin_amdgcn_rcpf(x); }
__device__ __forceinline__ float sigm(float s) { return fast_rcp(1.f + __expf(-s)); }
__device__ __forceinline__ float fast_tanh(float x) {
  return fmaf(2.f, fast_rcp(1.f + __expf(-2.f * x)), -1.f);
}
__device__ __forceinline__ float act_sel(float s, bool ist) {
  float z = ist ? s + s : s;
  float r = fast_rcp(1.f + __expf(-z));
  return ist ? fmaf(2.f, r, -1.f) : r;
}

// xor-32 partner, pure VALU; order-proof XOR extraction.
__device__ __forceinline__ float partner32(float x) {
  int xi = __builtin_bit_cast(int, x);
#if __has_builtin(__builtin_amdgcn_permlane32_swap)
  int2v r = __builtin_amdgcn_permlane32_swap(xi, xi, false, false);
  return __builtin_bit_cast(float, r.x ^ r.y ^ xi);
#else
  int a = xi, b = xi;
  asm("v_permlane32_swap_b32 %0, %1" : "+v"(a), "+v"(b));
  return __builtin_bit_cast(float, a ^ b ^ xi);
#endif
}

// xor-1 neighbor exchange via DPP quad_perm [1,0,3,2]
__device__ __forceinline__ float xor1_dpp(float x) {
  int xi = __builtin_bit_cast(int, x);
  int r = __builtin_amdgcn_update_dpp(xi, xi, 0xB1, 0xF, 0xF, true);
  return __builtin_bit_cast(float, r);
}

// 32-term dot via 4 independent pk_fma_f16 chains of 4, pairwise pk_add,
// 2x dot2 f32 merge. w, hp: 16 packed-f16 dwords each.
__device__ __forceinline__ float gdot16(const uint32_t* w, const uint32_t* hp,
                                        float acc) {
  h2v c0 = H2(w[0]) * H2(hp[0]);
  h2v c1 = H2(w[1]) * H2(hp[1]);
  h2v c2 = H2(w[2]) * H2(hp[2]);
  h2v c3 = H2(w[3]) * H2(hp[3]);
#pragma unroll
  for (int k = 4; k < 16; k += 4) {
    c0 += H2(w[k + 0]) * H2(hp[k + 0]);
    c1 += H2(w[k + 1]) * H2(hp[k + 1]);
    c2 += H2(w[k + 2]) * H2(hp[k + 2]);
    c3 += H2(w[k + 3]) * H2(hp[k + 3]);
  }
  h2v s01 = c0 + c1;
  h2v s23 = c2 + c3;
  acc = dot2(U32(s01), ONE2, acc);
  acc = dot2(U32(s23), ONE2, acc);
  return acc;
}

// dual 32-term dot (wi.h0 + wh.h1) via 8 chains, 4 pk_add, 4 dot2 merges.
__device__ __forceinline__ float gdot16x2(const uint32_t* wi, const uint32_t* wh,
                                          const uint32_t* h0, const uint32_t* h1,
                                          float acc) {
  h2v c0 = H2(wi[0]) * H2(h0[0]);
  h2v c1 = H2(wi[1]) * H2(h0[1]);
  h2v c2 = H2(wi[2]) * H2(h0[2]);
  h2v c3 = H2(wi[3]) * H2(h0[3]);
  h2v d0 = H2(wh[0]) * H2(h1[0]);
  h2v d1 = H2(wh[1]) * H2(h1[1]);
  h2v d2 = H2(wh[2]) * H2(h1[2]);
  h2v d3 = H2(wh[3]) * H2(h1[3]);
#pragma unroll
  for (int k = 4; k < 16; k += 4) {
    c0 += H2(wi[k + 0]) * H2(h0[k + 0]);
    c1 += H2(wi[k + 1]) * H2(h0[k + 1]);
    c2 += H2(wi[k + 2]) * H2(h0[k + 2]);
    c3 += H2(wi[k + 3]) * H2(h0[k + 3]);
    d0 += H2(wh[k + 0]) * H2(h1[k + 0]);
    d1 += H2(wh[k + 1]) * H2(h1[k + 1]);
    d2 += H2(wh[k + 2]) * H2(h1[k + 2]);
    d3 += H2(wh[k + 3]) * H2(h1[k + 3]);
  }
  h2v s01 = c0 + c1, s23 = c2 + c3;
  h2v t01 = d0 + d1, t23 = d2 + d3;
  acc = dot2(U32(s01), ONE2, acc);
  acc = dot2(U32(s23), ONE2, acc);
  acc = dot2(U32(t01), ONE2, acc);
  acc = dot2(U32(t23), ONE2, acc);
  return acc;
}

// ---------------- Phase 1: xg GEMM (unchanged) ----------------
__global__ __launch_bounds__(256) void xg_gemm(const float* __restrict__ x,
                                               const float* __restrict__ W,
                                               const float* __restrict__ bih,
                                               const float* __restrict__ bhh,
                                               float* __restrict__ outp) {
  __shared__ float xs[16][68];
  __shared__ float ws[16][128];
  const int tid = threadIdx.x;
  const int m0 = blockIdx.x * 64;
  const int tr = tid >> 5;
  const int tc = tid & 31;
  const int tm = tr * 8;
  const int tn = tc * 4;
  const int sxm = tid >> 2;
  const int sxk = (tid & 3) * 4;
  const int swg = tid >> 1;
  const int swk = (tid & 1) * 8;

  float acc[8][4];
#pragma unroll
  for (int i = 0; i < 8; ++i)
#pragma unroll
    for (int j = 0; j < 4; ++j) acc[i][j] = 0.f;

  for (int k0 = 0; k0 < DD; k0 += 16) {
    const float4 xv = *(const float4*)(x + (size_t)(m0 + sxm) * DD + k0 + sxk);
    xs[sxk + 0][sxm] = xv.x;
    xs[sxk + 1][sxm] = xv.y;
    xs[sxk + 2][sxm] = xv.z;
    xs[sxk + 3][sxm] = xv.w;
    const float4 wv0 = *(const float4*)(W + (size_t)swg * DD + k0 + swk);
    const float4 wv1 = *(const float4*)(W + (size_t)swg * DD + k0 + swk + 4);
    ws[swk + 0][swg] = wv0.x;
    ws[swk + 1][swg] = wv0.y;
    ws[swk + 2][swg] = wv0.z;
    ws[swk + 3][swg] = wv0.w;
    ws[swk + 4][swg] = wv1.x;
    ws[swk + 5][swg] = wv1.y;
    ws[swk + 6][swg] = wv1.z;
    ws[swk + 7][swg] = wv1.w;
    __syncthreads();
#pragma unroll
    for (int k = 0; k < 16; ++k) {
      const float4 a0 = *(const float4*)&xs[k][tm];
      const float4 a1 = *(const float4*)&xs[k][tm + 4];
      const float4 wv = *(const float4*)&ws[k][tn];
      const float xr[8] = {a0.x, a0.y, a0.z, a0.w, a1.x, a1.y, a1.z, a1.w};
      const float wr[4] = {wv.x, wv.y, wv.z, wv.w};
#pragma unroll
      for (int i = 0; i < 8; ++i)
#pragma unroll
        for (int j = 0; j < 4; ++j) acc[i][j] = fmaf(xr[i], wr[j], acc[i][j]);
    }
    __syncthreads();
  }
  const float4 bi = *(const float4*)(bih + tn);
  const float4 bh = *(const float4*)(bhh + tn);
  const float bs[4] = {bi.x + bh.x, bi.y + bh.y, bi.z + bh.z, bi.w + bh.w};
#pragma unroll
  for (int i = 0; i < 8; ++i) {
    float4 o;
    o.x = acc[i][0] + bs[0];
    o.y = acc[i][1] + bs[1];
    o.z = acc[i][2] + bs[2];
    o.w = acc[i][3] + bs[3];
    *(float4*)(outp + (size_t)(m0 + tm + i) * GG + tn) = o;
  }
}

// ---------------- Phase 2: single-wave-per-batch scan ----------------
__global__ __launch_bounds__(64, 1) void lstm_scan(const float* __restrict__ xg,
                                                   const float* __restrict__ Whh0,
                                                   const float* __restrict__ Wih1,
                                                   const float* __restrict__ Whh1,
                                                   const float* __restrict__ bih1,
                                                   const float* __restrict__ bhh1,
                                                   float* __restrict__ out) {
  const int l = threadIdx.x;
  const int j = l & 31;
  const int hi = l >> 5;
  const int b = blockIdx.x;
  const int gA = j + 64 * hi;
  const int gB = gA + 32;

  uint32_t w0A[16], w0B[16], wiA[16], whA[16], wiB[16], whB[16];
#pragma unroll
  for (int q = 0; q < 8; ++q) {
    float4 a = *(const float4*)(Whh0 + (size_t)gA * HH + q * 4);
    float4 c = *(const float4*)(Whh0 + (size_t)gB * HH + q * 4);
    w0A[2 * q] = pack2(a.x, a.y); w0A[2 * q + 1] = pack2(a.z, a.w);
    w0B[2 * q] = pack2(c.x, c.y); w0B[2 * q + 1] = pack2(c.z, c.w);
    float4 d = *(const float4*)(Wih1 + (size_t)gA * HH + q * 4);
    float4 e = *(const float4*)(Wih1 + (size_t)gB * HH + q * 4);
    wiA[2 * q] = pack2(d.x, d.y); wiA[2 * q + 1] = pack2(d.z, d.w);
    wiB[2 * q] = pack2(e.x, e.y); wiB[2 * q + 1] = pack2(e.z, e.w);
    float4 f = *(const float4*)(Whh1 + (size_t)gA * HH + q * 4);
    float4 g = *(const float4*)(Whh1 + (size_t)gB * HH + q * 4);
    whA[2 * q] = pack2(f.x, f.y); whA[2 * q + 1] = pack2(f.z, f.w);
    whB[2 * q] = pack2(g.x, g.y); whB[2 * q + 1] = pack2(g.z, g.w);
  }
  const float b1A = bih1[gA] + bhh1[gA];
  const float b1B = bih1[gB] + bhh1[gB];

  uint32_t h0p[16], h1p[16];  // wave-uniform packed-f16 h state (SGPRs)
#pragma unroll
  for (int k = 0; k < 16; ++k) { h0p[k] = 0u; h1p[k] = 0u; }
  float c0 = 0.f, c1 = 0.f;

  const float* xgp = xg + (size_t)b * TT * GG;
  float* outp = out + (size_t)b * TT * HH;

  float xA[4], xB[4];
#pragma unroll
  for (int u = 0; u < 4; ++u) {
    xA[u] = xgp[u * GG + gA];
    xB[u] = xgp[u * GG + gB];
  }

  for (int tb = 0; tb < TT; tb += 4) {
#pragma unroll
    for (int u = 0; u < 4; ++u) {
      const int t = tb + u;
      float sA0 = xA[u], sB0 = xB[u];
      const int tp = (t + 4 < TT) ? (t + 4) : (TT - 1);
      xA[u] = xgp[(size_t)tp * GG + gA];
      xB[u] = xgp[(size_t)tp * GG + gB];
      // ---- layer0 dots (h0p = h0[t-1]) ----
      sA0 = gdot16(w0A, h0p, sA0);
      sB0 = gdot16(w0B, h0p, sB0);
      // ---- layer1 dots for step t-1 (h0p=h0[t-1], h1p=h1[t-2]) ----
      float sA1 = gdot16x2(wiA, whA, h0p, h1p, b1A);
      float sB1 = gdot16x2(wiB, whB, h0p, h1p, b1B);
      // ---- layer0 combine -> h0[t] ----
      {
        float aA = act_sel(sA0, hi != 0);  // i (hi=0) / g (hi=1)
        float aB = sigm(sB0);              // f (hi=0) / o (hi=1)
        float pAx = partner32(aA);
        float pBx = partner32(aB);
        float gi = hi ? pAx : aA;
        float gf = hi ? pBx : aB;
        float gg = hi ? aA : pAx;
        float go = hi ? aB : pBx;
        c0 = fmaf(gf, c0, gi * gg);
        float h = go * fast_tanh(c0);
        float oth = xor1_dpp(h);
        float lo = (j & 1) ? oth : h;
        float hh = (j & 1) ? h : oth;
        uint32_t pk = pack2(lo, hh);
#pragma unroll
        for (int m = 0; m < 16; ++m)
          h0p[m] = (uint32_t)__builtin_amdgcn_readlane((int)pk, 2 * m);
      }
      // ---- layer1 combine for step t-1 ----
      if (t > 0) {
        float aA = act_sel(sA1, hi != 0);
        float aB = sigm(sB1);
        float pAx = partner32(aA);
        float pBx = partner32(aB);
        float gi = hi ? pAx : aA;
        float gf = hi ? pBx : aB;
        float gg = hi ? aA : pAx;
        float go = hi ? aB : pBx;
        c1 = fmaf(gf, c1, gi * gg);
        float h = go * fast_tanh(c1);
        if (!hi) outp[(size_t)(t - 1) * HH + j] = h;
        float oth = xor1_dpp(h);
        float lo = (j & 1) ? oth : h;
        float hh = (j & 1) ? h : oth;
        uint32_t pk = pack2(lo, hh);
#pragma unroll
        for (int m = 0; m < 16; ++m)
          h1p[m] = (uint32_t)__builtin_amdgcn_readlane((int)pk, 2 * m);
      }
    }
  }
  // ---- final layer1 step (t = TT-1) ----
  {
    float sA1 = gdot16x2(wiA, whA, h0p, h1p, b1A);
    float sB1 = gdot16x2(wiB, whB, h0p, h1p, b1B);
    float aA = act_sel(sA1, hi != 0);
    float aB = sigm(sB1);
    float pAx = partner32(aA);
    float pBx = partner32(aB);
    float gi = hi ? pAx : aA;
    float gf = hi ? pBx : aB;
    float gg = hi ? aA : pAx;
    float go = hi ? aB : pBx;
    c1 = fmaf(gf, c1, gi * gg);
    float h = go * fast_tanh(c1);
    if (!hi) outp[(size_t)(TT - 1) * HH + j] = h;
  }
}

extern "C" void kernel_launch(void* const* d_in, const int* in_sizes, int n_in,
                              void* d_out, int out_size, void* d_ws, size_t ws_size,
                              hipStream_t stream) {
  const float* x = (const float*)d_in[0];
  const float* Wih0 = (const float*)d_in[1];
  const float* Whh0 = (const float*)d_in[2];
  const float* bih0 = (const float*)d_in[3];
  const float* bhh0 = (const float*)d_in[4];
  const float* Wih1 = (const float*)d_in[5];
  const float* Whh1 = (const float*)d_in[6];
  const float* bih1 = (const float*)d_in[7];
  const float* bhh1 = (const float*)d_in[8];
  float* out = (float*)d_out;
  float* xg = (float*)d_ws;  // B*T*4H*4 = 33.5 MB scratch

  xg_gemm<<<dim3((BB * TT) / 64), dim3(256), 0, stream>>>(x, Wih0, bih0, bhh0, xg);
  lstm_scan<<<dim3(BB), dim3(64), 0, stream>>>(xg, Whh0, Wih1, Whh1, bih1, bhh1, out);
}